// Round 4
// baseline (668.633 us; speedup 1.0000x reference)
//
#include <hip/hip_runtime.h>
#include <stdint.h>
#include <stddef.h>

#define TDIM 4096
#define DDIM 1024
#define HDIM 64
#define BDIM 8
#define MROWS (BDIM * TDIM)   // 32768
#define KCAT (DDIM + HDIM)    // 1088
#define DD (DDIM * DDIM)
#define HD (HDIM * DDIM)

typedef unsigned short ushort_t;
typedef __attribute__((ext_vector_type(8))) short short8;
typedef __attribute__((ext_vector_type(4))) float floatx4;

__device__ __forceinline__ unsigned short f2bf(float f) {
  unsigned u = __float_as_uint(f);
  u += 0x7fffu + ((u >> 16) & 1u);          // round-to-nearest-even
  return (unsigned short)(u >> 16);
}
__device__ __forceinline__ float bf2f(unsigned short s) {
  return __uint_as_float(((unsigned)s) << 16);
}
__device__ __forceinline__ float softplusf(float x) {
  return x > 20.f ? x : log1pf(expf(x));
}

// ---------------- fused weight prep (one launch) ----------------
__global__ void k_prep(const float* __restrict__ W1, const float* __restrict__ W2,
                       const float* __restrict__ Wlast, const float* __restrict__ dwm,
                       const float* __restrict__ Bw, const float* __restrict__ Dw,
                       const float* __restrict__ Cw, const float* __restrict__ Cb,
                       const float* __restrict__ Db,
                       ushort_t* __restrict__ wcat, ushort_t* __restrict__ wlb,
                       ushort_t* __restrict__ dwbw, ushort_t* __restrict__ bcat,
                       float* __restrict__ biasCD) {
  int i = blockIdx.x * 256 + threadIdx.x;
  if (i < DD) { wcat[i] = f2bf(W1[i]); return; }
  i -= DD;
  if (i < DD) { wcat[DD + i] = f2bf(W2[i]); return; }
  i -= DD;
  if (i < DD) { wlb[i] = f2bf(Wlast[i]); return; }
  i -= DD;
  if (i < HD) { dwbw[i] = f2bf(dwm[i]); return; }
  i -= HD;
  if (i < HD) { dwbw[HD + i] = f2bf(Bw[i]); return; }
  i -= HD;
  if (i < DDIM * KCAT) {
    const int row = i / KCAT, k = i - row * KCAT;
    const float v = (k < DDIM) ? Dw[row * DDIM + k] : Cw[row * HDIM + (k - DDIM)];
    bcat[i] = f2bf(v);
    return;
  }
  i -= DDIM * KCAT;
  if (i < DDIM) biasCD[i] = Cb[i] + Db[i];
}

// ---------------- RMSNorm: x (f32) -> xn (bf16) ----------------
__global__ __launch_bounds__(256) void k_rms(const float* __restrict__ x,
                                             const float* __restrict__ nw,
                                             ushort_t* __restrict__ xn) {
  const int row = blockIdx.x;
  const int tid = threadIdx.x;
  const size_t base = (size_t)row * DDIM + tid * 4;
  const float4 xv = *(const float4*)(x + base);
  float ss = xv.x * xv.x + xv.y * xv.y + xv.z * xv.z + xv.w * xv.w;
  for (int off = 32; off > 0; off >>= 1) ss += __shfl_down(ss, off, 64);
  __shared__ float sws[4];
  const int lane = tid & 63, w = tid >> 6;
  if (lane == 0) sws[w] = ss;
  __syncthreads();
  const float tot = sws[0] + sws[1] + sws[2] + sws[3];
  const float scale = rsqrtf(tot * (1.0f / DDIM) + 1.1920929e-7f);
  const float4 nwv = *(const float4*)(nw + tid * 4);
  ushort4 o;
  o.x = f2bf(xv.x * scale * nwv.x);
  o.y = f2bf(xv.y * scale * nwv.y);
  o.z = f2bf(xv.z * scale * nwv.z);
  o.w = f2bf(xv.w * scale * nwv.w);
  *(ushort4*)(xn + base) = o;
}

// ---------------- causal depthwise conv k=3 + silu: sliding-window x8 rows ----------------
// Each thread owns 8 consecutive t-rows for one 8-wide d-chunk; keeps a 2-row
// register window so each x_b row is read ~1.25x instead of 3x (192 -> 80 MiB).
__global__ __launch_bounds__(256) void k_conv(const ushort_t* __restrict__ xz,
                                              const float* __restrict__ cw,
                                              const float* __restrict__ cb,
                                              ushort_t* __restrict__ acat) {
  const int gt = blockIdx.x * 256 + threadIdx.x;   // 0 .. MROWS*DDIM/64 - 1
  const int dc = (gt & 127) * 8;                   // d-chunk base (wave: 1KB contiguous)
  const size_t m0 = (size_t)(gt >> 7) * 8;         // 8-row group (never crosses batch)
  const int t0 = (int)(m0 & (TDIM - 1));
  float w0[8], w1[8], w2[8], bb[8];
#pragma unroll
  for (int e = 0; e < 8; ++e) {
    w0[e] = cw[(dc + e) * 3 + 0];
    w1[e] = cw[(dc + e) * 3 + 1];
    w2[e] = cw[(dc + e) * 3 + 2];
    bb[e] = cb[dc + e];
  }
  const size_t s0 = m0 * 2048 + dc;
  short8 r0 = {0,0,0,0,0,0,0,0}, r1 = {0,0,0,0,0,0,0,0};
  if (t0 >= 2) {   // t0 is a multiple of 8, so t0>=2 <=> t0>0
    r0 = *(const short8*)(xz + s0 - 4096);
    r1 = *(const short8*)(xz + s0 - 2048);
  }
#pragma unroll
  for (int dt = 0; dt < 8; ++dt) {
    const short8 r2 = *(const short8*)(xz + s0 + (size_t)dt * 2048);
    short8 o;
#pragma unroll
    for (int e = 0; e < 8; ++e) {
      float v = bf2f((ushort_t)r2[e]) * w2[e]
              + bf2f((ushort_t)r1[e]) * w1[e]
              + bf2f((ushort_t)r0[e]) * w0[e]
              + bb[e];
      o[e] = (short)f2bf(v / (1.f + __expf(-v)));
    }
    *(short8*)(acat + (m0 + dt) * KCAT + dc) = o;
    r0 = r1; r1 = r2;
  }
}

// ---------------- block scan: wave shfl_up scan + 4-entry cross-wave fixup ----------------
__device__ __forceinline__ float block_scan_excl(float run, int tid, float* shp) {
  const int lane = tid & 63, w = tid >> 6;
  float s = run;
#pragma unroll
  for (int off = 1; off < 64; off <<= 1) {
    const float u = __shfl_up(s, off, 64);
    if (lane >= off) s += u;
  }
  __syncthreads();                  // protect shp reuse across calls
  if (lane == 63) shp[w] = s;
  __syncthreads();
  float wo = 0.f;
#pragma unroll
  for (int i = 0; i < 3; ++i) wo += (i < w) ? shp[i] : 0.f;
  return wo + s - run;              // exclusive prefix across 256 threads
}

// ---------------- fused delta + selective scan: one block per (b,h) channel ----------------
__global__ __launch_bounds__(256) void k_scan(const float* __restrict__ preG,
                                              const float* __restrict__ db,
                                              const float* __restrict__ Bb,
                                              const float* __restrict__ A,
                                              ushort_t* __restrict__ hT) {
  const int ch = blockIdx.x;           // 0..511
  const int b = ch >> 6, h = ch & 63;
  const int tid = threadIdx.x;
  const float dbh = db[h], Bbh = Bb[h];
  const float al = -softplusf(A[h]);
  const size_t base1 = (size_t)h * MROWS + (size_t)b * TDIM + (size_t)tid * 16;
  const size_t base2 = base1 + (size_t)64 * MROWS;

  float a[16], bbv[16];
#pragma unroll
  for (int k4 = 0; k4 < 4; ++k4) {
    const float4 p1 = *(const float4*)(preG + base1 + k4 * 4);
    const float4 p2 = *(const float4*)(preG + base2 + k4 * 4);
    const float pp1[4] = {p1.x, p1.y, p1.z, p1.w};
    const float pp2[4] = {p2.x, p2.y, p2.z, p2.w};
#pragma unroll
    for (int e = 0; e < 4; ++e) {
      const float delta = softplusf(pp1[e] + dbh);
      a[k4 * 4 + e] = delta * al;
      bbv[k4 * 4 + e] = delta * (pp2[e] + Bbh);
    }
  }
  float run = 0.f;
#pragma unroll
  for (int k = 0; k < 16; ++k) { run += a[k]; a[k] = run; }  // local inclusive

  __shared__ float shp[4];
  const float off = block_scan_excl(run, tid, shp);

  float term[16];
  float prev = off;  // exclusive prefix (unclipped)
#pragma unroll
  for (int k = 0; k < 16; ++k) {
    const float Pk = off + a[k];
    const float Ashift = fminf(fmaxf(prev, -20.f), 20.f);
    term[k] = bbv[k] * expf(-Ashift);
    a[k] = fminf(fmaxf(Pk, -20.f), 20.f);  // clipped A_cum
    prev = Pk;
  }

  float run2 = 0.f;
#pragma unroll
  for (int k = 0; k < 16; ++k) { run2 += term[k]; term[k] = run2; }
  const float off2 = block_scan_excl(run2, tid, shp);

  ushort_t* dst = hT + (size_t)h * MROWS + (size_t)b * TDIM + (size_t)tid * 16;
#pragma unroll
  for (int k = 0; k < 16; ++k) {
    dst[k] = f2bf(expf(a[k]) * (off2 + term[k]));
  }
}

// ---------------- transpose hT[64][M] -> acat[:, 1024:1088] ----------------
__global__ __launch_bounds__(256) void k_htrans(const ushort_t* __restrict__ hT,
                                                ushort_t* __restrict__ acat) {
  __shared__ ushort_t t[64 * 256];
  const int tid = threadIdx.x;
  const int m0 = blockIdx.x * 256;
#pragma unroll
  for (int p = 0; p < 8; ++p) {
    const int e = p * 2048 + tid * 8;
    const int h = e >> 8, mm = e & 255;
    *(short8*)(t + e) = *(const short8*)(hT + (size_t)h * MROWS + m0 + mm);
  }
  __syncthreads();
  ushort_t* dst = acat + (size_t)(m0 + tid) * KCAT + DDIM;
#pragma unroll
  for (int p = 0; p < 8; ++p) {
    short8 v;
#pragma unroll
    for (int e = 0; e < 8; ++e) v[e] = t[(p * 8 + e) * 256 + tid];
    *(short8*)(dst + p * 8) = v;
  }
}

// ---------------- 128x128 GEMM body (proven 2-phase); distinct wrappers per step ----------------
__device__ __forceinline__ void stage128x64(const ushort_t* __restrict__ G, int row0,
                                            int ld, int kc, ushort_t* s, int wave, int lane) {
  const int rsub = lane >> 3;   // row within 8-row group
  const int cpos = lane & 7;    // dest chunk position
  using gp_t = const unsigned int __attribute__((address_space(1)))*;
  using lp_t = unsigned int __attribute__((address_space(3)))*;
#pragma unroll
  for (int g = 0; g < 4; ++g) {
    const int rg = wave * 4 + g;           // 0..15 row-group
    const int r = rg * 8 + rsub;           // tile row
    const int c = cpos ^ rsub;             // source chunk (r&7 == rsub)
    const ushort_t* src = G + (size_t)(row0 + r) * (size_t)ld + (size_t)(kc + c * 8);
    __builtin_amdgcn_global_load_lds((gp_t)(const void*)src, (lp_t)(void*)(s + rg * 512),
                                     16, 0, 0);
  }
}

template <int MODE>
__device__ __forceinline__ void gemm128_body(
    const ushort_t* __restrict__ A, int lda,
    const ushort_t* __restrict__ Bt, int ldb,
    int nB, int Kdim,
    float* __restrict__ outF, ushort_t* __restrict__ outB, int ldc,
    const float* __restrict__ bias,
    const ushort_t* __restrict__ zmat, int ldz,
    const float* __restrict__ resid) {
  __shared__ alignas(16) ushort_t smem[128 * 128];  // 32KB: sA | sB, reused as C-tile
  ushort_t* sA = smem;
  ushort_t* sB = smem + 128 * 64;
  const int tid = threadIdx.x;
  const int wave = tid >> 6, lane = tid & 63;

  // XCD swizzle: consecutive slots on one XCD walk n fastest -> A-strip reuse in L2
  const int per = gridDim.x >> 3;
  const int xcd = blockIdx.x & 7, slot = blockIdx.x >> 3;
  const int tile = xcd * per + slot;
  const int m0 = (tile / nB) * 128, n0 = (tile % nB) * 128;

  const int half_m = (wave & 1) * 64, half_n = (wave >> 1) * 64;
  const int quad = lane >> 4, l16 = lane & 15;

  floatx4 acc[4][4];
#pragma unroll
  for (int i = 0; i < 4; ++i)
#pragma unroll
    for (int j = 0; j < 4; ++j) acc[i][j] = floatx4{0.f, 0.f, 0.f, 0.f};

  for (int kc = 0; kc < Kdim; kc += 64) {
    stage128x64(A, m0, lda, kc, sA, wave, lane);
    stage128x64(Bt, n0, ldb, kc, sB, wave, lane);
    __syncthreads();
#pragma unroll
    for (int s = 0; s < 2; ++s) {
      short8 af[4], bfr[4];
#pragma unroll
      for (int i = 0; i < 4; ++i) {
        const int r = half_m + i * 16 + l16;
        const int cp = (s * 4 + quad) ^ (r & 7);
        af[i] = *(const short8*)(sA + r * 64 + cp * 8);
      }
#pragma unroll
      for (int j = 0; j < 4; ++j) {
        const int r = half_n + j * 16 + l16;
        const int cp = (s * 4 + quad) ^ (r & 7);
        bfr[j] = *(const short8*)(sB + r * 64 + cp * 8);
      }
#pragma unroll
      for (int i = 0; i < 4; ++i)
#pragma unroll
        for (int j = 0; j < 4; ++j)
          acc[i][j] = __builtin_amdgcn_mfma_f32_16x16x32_bf16(af[i], bfr[j], acc[i][j], 0, 0, 0);
    }
    __syncthreads();
  }

  // Epilogue through LDS: acc (C/D layout col=lane&15, row=quad*4+reg) -> bf16 tile
#pragma unroll
  for (int i = 0; i < 4; ++i)
#pragma unroll
    for (int j = 0; j < 4; ++j)
#pragma unroll
      for (int rg = 0; rg < 4; ++rg) {
        const int r = half_m + i * 16 + quad * 4 + rg;
        const int c = half_n + j * 16 + l16;
        smem[r * 128 + c] = f2bf(acc[i][j][rg]);
      }
  __syncthreads();

#pragma unroll
  for (int p = 0; p < 8; ++p) {
    const int r = p * 16 + (tid >> 4);
    const int c = (tid & 15) * 8;
    short8 v8 = *(const short8*)(smem + r * 128 + c);
    const size_t m = (size_t)(m0 + r);
    const int n = n0 + c;
    if (MODE == 0) {
      *(short8*)(outB + m * (size_t)ldc + n) = v8;
    } else if (MODE == 1) {
      float* o = outF + m * (size_t)ldc + n;
#pragma unroll
      for (int e = 0; e < 8; ++e) o[e] = bf2f((ushort_t)v8[e]);
    } else if (MODE == 2) {
      const short8 z8 = *(const short8*)(zmat + m * (size_t)ldz + n);
      short8 o;
#pragma unroll
      for (int e = 0; e < 8; ++e) {
        const float v = bf2f((ushort_t)v8[e]) + bias[n + e];
        const float zf = bf2f((ushort_t)z8[e]);
        o[e] = (short)f2bf(v * (zf / (1.f + __expf(-zf))));
      }
      *(short8*)(outB + m * (size_t)ldc + n) = o;
    } else {
      const float* rs = resid + m * (size_t)ldc + n;
      float* o = outF + m * (size_t)ldc + n;
#pragma unroll
      for (int e = 0; e < 8; ++e) o[e] = bf2f((ushort_t)v8[e]) + rs[e];
    }
  }
}

// Distinct names so rocprof attributes duration per pipeline step.
__global__ __launch_bounds__(256, 4) void k_gemm_s2(
    const ushort_t* __restrict__ A, int lda, const ushort_t* __restrict__ Bt, int ldb,
    int nB, int Kdim, float* __restrict__ outF, ushort_t* __restrict__ outB, int ldc,
    const float* __restrict__ bias, const ushort_t* __restrict__ zmat, int ldz,
    const float* __restrict__ resid) {
  gemm128_body<0>(A, lda, Bt, ldb, nB, Kdim, outF, outB, ldc, bias, zmat, ldz, resid);
}
__global__ __launch_bounds__(256, 4) void k_gemm_s4(
    const ushort_t* __restrict__ A, int lda, const ushort_t* __restrict__ Bt, int ldb,
    int nB, int Kdim, float* __restrict__ outF, ushort_t* __restrict__ outB, int ldc,
    const float* __restrict__ bias, const ushort_t* __restrict__ zmat, int ldz,
    const float* __restrict__ resid) {
  gemm128_body<1>(A, lda, Bt, ldb, nB, Kdim, outF, outB, ldc, bias, zmat, ldz, resid);
}
__global__ __launch_bounds__(256, 4) void k_gemm_s7(
    const ushort_t* __restrict__ A, int lda, const ushort_t* __restrict__ Bt, int ldb,
    int nB, int Kdim, float* __restrict__ outF, ushort_t* __restrict__ outB, int ldc,
    const float* __restrict__ bias, const ushort_t* __restrict__ zmat, int ldz,
    const float* __restrict__ resid) {
  gemm128_body<2>(A, lda, Bt, ldb, nB, Kdim, outF, outB, ldc, bias, zmat, ldz, resid);
}
__global__ __launch_bounds__(256, 4) void k_gemm_s8(
    const ushort_t* __restrict__ A, int lda, const ushort_t* __restrict__ Bt, int ldb,
    int nB, int Kdim, float* __restrict__ outF, ushort_t* __restrict__ outB, int ldc,
    const float* __restrict__ bias, const ushort_t* __restrict__ zmat, int ldz,
    const float* __restrict__ resid) {
  gemm128_body<3>(A, lda, Bt, ldb, nB, Kdim, outF, outB, ldc, bias, zmat, ldz, resid);
}

// ---------------- host ----------------
extern "C" void kernel_launch(void* const* d_in, const int* in_sizes, int n_in,
                              void* d_out, int out_size, void* d_ws, size_t ws_size,
                              hipStream_t stream) {
  const float* x      = (const float*)d_in[0];
  const float* norm_w = (const float*)d_in[1];
  const float* W1     = (const float*)d_in[2];
  const float* W2     = (const float*)d_in[3];
  const float* Wlast  = (const float*)d_in[4];
  const float* conv_w = (const float*)d_in[5];
  const float* conv_b = (const float*)d_in[6];
  const float* Aarr   = (const float*)d_in[7];
  const float* Bw     = (const float*)d_in[8];
  const float* Bb     = (const float*)d_in[9];
  const float* Cw     = (const float*)d_in[10];
  const float* Cb     = (const float*)d_in[11];
  const float* Dw     = (const float*)d_in[12];
  const float* Db     = (const float*)d_in[13];
  const float* dwm    = (const float*)d_in[14];
  const float* dbv    = (const float*)d_in[15];

  char* ws = (char*)d_ws;
  // workspace plan (bytes):
  ushort_t* xz   = (ushort_t*)(ws + 0);           // M x 2048 bf16 (x_b | z), 128 MB
  ushort_t* acat = (ushort_t*)(ws + 134217728);   // M x 1088 bf16 (xc | h), ~68 MB
  float*   preG  = (float*)(ws + 205520896);      // 128 x M f32 (transposed), 16 MB
  ushort_t* hT   = (ushort_t*)(ws + 222298112);   // 64 x M bf16, 4 MB
  ushort_t* xnu  = (ushort_t*)(ws + 226492416);   // M x 1024 bf16: xn, later u. 64 MB
  ushort_t* wcat = (ushort_t*)(ws + 293601280);   // 2048 x 1024 bf16 (W1; W2), 4 MB
  ushort_t* wlb  = (ushort_t*)(ws + 297795584);   // 1024 x 1024 bf16, 2 MB
  ushort_t* dwbw = (ushort_t*)(ws + 299892736);   // 128 x 1024 bf16 (dw; Bw), 256 KB
  ushort_t* bcat = (ushort_t*)(ws + 300154880);   // 1024 x 1088 bf16 (Dw | Cw), ~2.2 MB
  float*  biasCD = (float*)(ws + 302383104);      // 1024 f32
  float*   outF  = (float*)d_out;

  // 0. fused weight prep (one launch)
  {
    const int total = 3 * DD + 2 * HD + DDIM * KCAT + DDIM;
    k_prep<<<(total + 255) / 256, 256, 0, stream>>>(W1, W2, Wlast, dwm, Bw, Dw, Cw, Cb, Db,
                                                    wcat, wlb, dwbw, bcat, biasCD);
  }

  // 1. RMSNorm -> xn
  k_rms<<<MROWS, 256, 0, stream>>>(x, norm_w, xnu);

  // 2. [x_b | z] = xn @ [W1;W2].T  (fused, N=2048)
  k_gemm_s2<<<256 * 16, 256, 0, stream>>>(xnu, DDIM, wcat, DDIM, 16, DDIM,
                                          nullptr, xz, 2048, nullptr, nullptr, 0, nullptr);

  // 3. conv + silu -> acat cols [0,1024)  (sliding-window, 8 rows/thread)
  k_conv<<<(MROWS * DDIM) / (256 * 64), 256, 0, stream>>>(xz, conv_w, conv_b, acat);

  // 4. preG_T = [dw;Bw] @ xc.T  (operand-swapped: output 128 x M row-major, coalesced)
  k_gemm_s4<<<256, 256, 0, stream>>>(dwbw, DDIM, acat, KCAT, 256, DDIM,
                                     preG, nullptr, MROWS, nullptr, nullptr, 0, nullptr);

  // 5+6. fused delta + selective scan -> hT (transposed)
  k_scan<<<BDIM * HDIM, 256, 0, stream>>>(preG, dbv, Bb, Aarr, hT);

  // 6b. transpose hT into acat cols [1024,1088)
  k_htrans<<<MROWS / 256, 256, 0, stream>>>(hT, acat);

  // 7. u = (h@Cw.T + xc@Dw.T + Cb + Db) * silu(z)   (K=1088 concat GEMM)
  k_gemm_s7<<<256 * 8, 256, 0, stream>>>(acat, KCAT, bcat, KCAT, 8, KCAT,
                                         nullptr, xnu, DDIM, biasCD, xz + DDIM, 2048, nullptr);

  // 8. out = u @ Wlast.T + x
  k_gemm_s8<<<256 * 8, 256, 0, stream>>>(xnu, DDIM, wlb, DDIM, 8, DDIM,
                                         outF, nullptr, DDIM, nullptr, nullptr, 0, x);

  (void)in_sizes; (void)n_in; (void)out_size; (void)ws_size;
}